// Round 5
// baseline (142.443 us; speedup 1.0000x reference)
//
#include <hip/hip_runtime.h>

// Problem constants
#define NB      20000      // nodes per batch
#define BATCH   4
#define KNN     16
#define DD      128        // embedding dim
#define M_TOTAL (BATCH*NB) // 80000 rows
#define BM      64         // nodes per block
#define MW      136        // LDS row stride (bf16 elems), padded from 128
#define NSLOT   157        // blocks per XCD group (157*64*2 >= 20000 rows/batch)
#define GRID_MAIN (8*NSLOT)

typedef __attribute__((ext_vector_type(8))) short          bf16x8;
typedef __attribute__((ext_vector_type(4))) float          f32x4;
typedef __attribute__((ext_vector_type(4))) int            i32x4;
typedef __attribute__((ext_vector_type(8))) unsigned short u16x8;

__device__ __forceinline__ unsigned short f2bf(float f) {
    unsigned int u = __float_as_uint(f);
    u += 0x7fffu + ((u >> 16) & 1u);           // round-to-nearest-even
    return (unsigned short)(u >> 16);
}
__device__ __forceinline__ float bf2f(unsigned short u) {
    return __uint_as_float((unsigned int)u << 16);
}

// ---- weights prep: fold concat into W1a = W1x+W1d, W1b = W1m-W1d (transposed,
//      bf16 [col][k]); W2 -> W2T. 3*16384 elems, 192 blocks.
__global__ __launch_bounds__(256) void nr_prep_w(
    const float* __restrict__ W1, const float* __restrict__ W2,
    unsigned short* __restrict__ W1aT, unsigned short* __restrict__ W1bT,
    unsigned short* __restrict__ W2T)
{
    int tid = blockIdx.x * 256 + threadIdx.x;   // < 49152
    int col = (tid & 16383) / DD;
    int k   = (tid & 16383) % DD;
    if (tid < 16384) {
        W1aT[tid] = f2bf(W1[k * DD + col] + W1[(256 + k) * DD + col]);
    } else if (tid < 32768) {
        W1bT[tid - 16384] = f2bf(W1[(128 + k) * DD + col] - W1[(256 + k) * DD + col]);
    } else {
        W2T[tid - 32768] = f2bf(W2[k * DD + col]);
    }
}

// ---- emb prep: contiguous f32 -> bf16, 8 elems/thread (5000 blocks)
__global__ __launch_bounds__(256) void nr_prep_emb(
    const float* __restrict__ src, unsigned short* __restrict__ dst)
{
    long long i = ((long long)blockIdx.x * 256 + threadIdx.x) * 8;
    const float4* p = (const float4*)(src + i);
    float4 a = p[0], b = p[1];
    u16x8 o;
    o[0]=f2bf(a.x); o[1]=f2bf(a.y); o[2]=f2bf(a.z); o[3]=f2bf(a.w);
    o[4]=f2bf(b.x); o[5]=f2bf(b.y); o[6]=f2bf(b.z); o[7]=f2bf(b.w);
    *(u16x8*)(dst + i) = o;
}

// MODE 0: bf16 table (embh = full B*N row table). MODE 2: f32 fallback.
// Grid is 8*NSLOT; blockIdx&7 selects the XCD (measured round-robin dispatch);
// XCD pair (x>>1) owns one batch so each XCD L2 sees only that batch's table.
template<int MODE>
__global__ __launch_bounds__(256, 4) void nr_main(
    const float* __restrict__ emb, const unsigned short* __restrict__ embh,
    const int* __restrict__ knn,
    const unsigned short* __restrict__ W1aT, const unsigned short* __restrict__ W1bT,
    const unsigned short* __restrict__ W2T,
    const float* __restrict__ b1, const float* __restrict__ b2,
    float* __restrict__ out)
{
    extern __shared__ unsigned short lds[];     // [64][MW] mean, reused for h;
                                                // MODE2 adds x region behind it
    unsigned short* ldsx = lds + BM * MW;       // MODE2 only

    const int t     = threadIdx.x;
    const int xcd   = blockIdx.x & 7;
    const int slot  = blockIdx.x >> 3;          // 0..NSLOT-1
    const int batch = xcd >> 1;
    const int bib   = (xcd & 1) * NSLOT + slot; // 0..313
    const int m_base = batch * NB + bib * BM;
    const int mend   = batch * NB + NB;

    // -------- Phase 1: gather 16 neighbors, mean -> LDS (bf16)
    {
        const int node_local = t >> 2;          // 0..63
        const int dpart      = t & 3;           // 32 dims each
        int m = m_base + node_local;
        if (m >= mend) m = mend - 1;            // tail dup (results discarded)

        int idx[KNN];
        const i32x4* kp4 = (const i32x4*)(knn + (long long)m * KNN);
        #pragma unroll
        for (int q = 0; q < 4; ++q) {
            i32x4 v = __builtin_nontemporal_load(kp4 + q);
            idx[4*q+0] = v[0]; idx[4*q+1] = v[1]; idx[4*q+2] = v[2]; idx[4*q+3] = v[3];
        }

        float sm[32];
        #pragma unroll
        for (int e = 0; e < 32; ++e) sm[e] = 0.f;

        if constexpr (MODE == 0) {
            const unsigned short* nb_base =
                embh + (long long)batch * NB * DD + dpart * 32;
            u16x8 va[4], vb[4];
            {   const u16x8* p = (const u16x8*)(nb_base + (long long)idx[0] * DD);
                va[0]=p[0]; va[1]=p[1]; va[2]=p[2]; va[3]=p[3]; }
            auto accum = [&](const u16x8* v) {
                #pragma unroll
                for (int j = 0; j < 4; ++j)
                    #pragma unroll
                    for (int e = 0; e < 8; ++e) sm[j*8+e] += bf2f(v[j][e]);
            };
            #pragma unroll
            for (int k = 0; k < KNN; ++k) {
                if (k + 1 < KNN) {
                    const u16x8* p = (const u16x8*)(nb_base + (long long)idx[k+1] * DD);
                    if ((k & 1) == 0) { vb[0]=p[0]; vb[1]=p[1]; vb[2]=p[2]; vb[3]=p[3]; }
                    else              { va[0]=p[0]; va[1]=p[1]; va[2]=p[2]; va[3]=p[3]; }
                }
                if ((k & 1) == 0) accum(va); else accum(vb);
            }
        } else {
            // f32 fallback: also build x (bf16) in ldsx
            const float4* xp = (const float4*)(emb + (long long)m * DD + dpart * 32);
            unsigned short* xrow = ldsx + node_local * MW + dpart * 32;
            #pragma unroll
            for (int j = 0; j < 8; ++j) {
                float4 v = xp[j];
                xrow[j*4+0]=f2bf(v.x); xrow[j*4+1]=f2bf(v.y);
                xrow[j*4+2]=f2bf(v.z); xrow[j*4+3]=f2bf(v.w);
            }
            const long long bbase = (long long)batch * NB * DD + dpart * 32;
            #pragma unroll 4
            for (int k = 0; k < KNN; ++k) {
                const float4* np = (const float4*)(emb + bbase + (long long)idx[k] * DD);
                #pragma unroll
                for (int j = 0; j < 8; ++j) {
                    float4 v = np[j];
                    sm[j*4+0]+=v.x; sm[j*4+1]+=v.y; sm[j*4+2]+=v.z; sm[j*4+3]+=v.w;
                }
            }
        }

        unsigned short* mrow = lds + node_local * MW + dpart * 32;
        #pragma unroll
        for (int j = 0; j < 4; ++j) {
            u16x8 pm;
            #pragma unroll
            for (int e = 0; e < 8; ++e) pm[e] = f2bf(sm[j*8+e] * 0.0625f);
            *(u16x8*)(mrow + j*8) = pm;
        }
    }
    __syncthreads();

    // -------- Phase 2: GEMM1  h_pre = x@W1a + m@W1b  (K=128 each)
    const int wave = t >> 6;
    const int lane = t & 63;
    const int lrow = lane & 15;                 // A row / B col / D col
    const int lk   = lane >> 4;                 // 0..3

    const int row_g = m_base + wave * 16 + lrow;
    const int rowA  = (row_g < mend) ? row_g : (mend - 1);

    bf16x8 xf[4], mf[4];
    if constexpr (MODE == 0) {
        const unsigned short* xr = embh + (long long)rowA * DD + lk * 8;
        #pragma unroll
        for (int ks = 0; ks < 4; ++ks) xf[ks] = *(const bf16x8*)(xr + ks * 32);
    } else {
        const unsigned short* xr = ldsx + (wave * 16 + lrow) * MW + lk * 8;
        #pragma unroll
        for (int ks = 0; ks < 4; ++ks) xf[ks] = *(const bf16x8*)(xr + ks * 32);
    }
    {
        const unsigned short* mr = lds + (wave * 16 + lrow) * MW + lk * 8;
        #pragma unroll
        for (int ks = 0; ks < 4; ++ks) mf[ks] = *(const bf16x8*)(mr + ks * 32);
    }

    f32x4 acc[8];
    #pragma unroll
    for (int f = 0; f < 8; ++f) acc[f] = (f32x4){0.f, 0.f, 0.f, 0.f};

    #pragma unroll
    for (int ks = 0; ks < 4; ++ks) {
        #pragma unroll
        for (int f = 0; f < 8; ++f) {
            int col = f * 16 + lrow;
            bf16x8 bw = *(const bf16x8*)(W1aT + col * DD + ks * 32 + lk * 8);
            acc[f] = __builtin_amdgcn_mfma_f32_16x16x32_bf16(xf[ks], bw, acc[f], 0, 0, 0);
        }
    }
    #pragma unroll
    for (int ks = 0; ks < 4; ++ks) {
        #pragma unroll
        for (int f = 0; f < 8; ++f) {
            int col = f * 16 + lrow;
            bf16x8 bw = *(const bf16x8*)(W1bT + col * DD + ks * 32 + lk * 8);
            acc[f] = __builtin_amdgcn_mfma_f32_16x16x32_bf16(mf[ks], bw, acc[f], 0, 0, 0);
        }
    }
    __syncthreads();                            // mean reads done -> overwrite with h

    // epilogue 1: bias + exact GELU -> h (bf16) into SAME LDS region
    #pragma unroll
    for (int f = 0; f < 8; ++f) {
        int col = f * 16 + lrow;
        float bb = b1[col];
        #pragma unroll
        for (int r = 0; r < 4; ++r) {
            int row = wave * 16 + lk * 4 + r;
            float xg = acc[f][r] + bb;
            float hv = 0.5f * xg * (1.0f + erff(xg * 0.70710678118654752f));
            lds[row * MW + col] = f2bf(hv);
        }
    }
    __syncthreads();

    // -------- Phase 3: GEMM2  upd = h @ W2
    f32x4 acc2[8];
    #pragma unroll
    for (int f = 0; f < 8; ++f) acc2[f] = (f32x4){0.f, 0.f, 0.f, 0.f};
    {
        const unsigned short* abase = lds + (wave * 16 + lrow) * MW + lk * 8;
        #pragma unroll
        for (int ks = 0; ks < 4; ++ks) {
            bf16x8 af = *(const bf16x8*)(abase + ks * 32);
            #pragma unroll
            for (int f = 0; f < 8; ++f) {
                int col = f * 16 + lrow;
                bf16x8 bw = *(const bf16x8*)(W2T + col * DD + ks * 32 + lk * 8);
                acc2[f] = __builtin_amdgcn_mfma_f32_16x16x32_bf16(af, bw, acc2[f], 0, 0, 0);
            }
        }
    }

    // epilogue 2: residual + bias, fp32 out (residual from bf16 table in MODE 0)
    #pragma unroll
    for (int f = 0; f < 8; ++f) {
        int col = f * 16 + lrow;
        float bb = b2[col];
        #pragma unroll
        for (int r = 0; r < 4; ++r) {
            int row = wave * 16 + lk * 4 + r;
            int rg  = m_base + row;
            if (rg < mend) {
                long long o = (long long)rg * DD + col;
                float res = (MODE == 0) ? bf2f(embh[o])
                                        : __builtin_nontemporal_load(emb + o);
                __builtin_nontemporal_store(res + acc2[f][r] + bb, out + o);
            }
        }
    }
}

extern "C" void kernel_launch(void* const* d_in, const int* in_sizes, int n_in,
                              void* d_out, int out_size, void* d_ws, size_t ws_size,
                              hipStream_t stream) {
    const float* emb = (const float*)d_in[0];   // [B,N,D] f32
    const int*   knn = (const int*)  d_in[1];   // [B,N,K] i32
    const float* W1  = (const float*)d_in[2];   // [384,128]
    const float* b1  = (const float*)d_in[3];   // [128]
    const float* W2  = (const float*)d_in[4];   // [128,128]
    const float* b2  = (const float*)d_in[5];   // [128]
    float* out = (float*)d_out;

    unsigned short* W1aT = (unsigned short*)d_ws;           // 16384 u16
    unsigned short* W1bT = W1aT + 16384;                    // 16384 u16
    unsigned short* W2T  = W1bT + 16384;                    // 16384 u16
    unsigned short* embh = W2T  + 16384;                    // 10,240,000 u16

    const size_t NEED_T1 = (size_t)(49152 + 10240000) * 2;

    nr_prep_w<<<192, 256, 0, stream>>>(W1, W2, W1aT, W1bT, W2T);

    if (ws_size >= NEED_T1) {
        nr_prep_emb<<<5000, 256, 0, stream>>>(emb, embh);   // 5000*2048 = 10.24M
        nr_main<0><<<GRID_MAIN, 256, BM * MW * 2, stream>>>(
            emb, embh, knn, W1aT, W1bT, W2T, b1, b2, out);
    } else {
        nr_main<2><<<GRID_MAIN, 256, 2 * BM * MW * 2, stream>>>(
            emb, nullptr, knn, W1aT, W1bT, W2T, b1, b2, out);
    }
}

// Round 6
// 126.164 us; speedup vs baseline: 1.1290x; 1.1290x over previous
//
#include <hip/hip_runtime.h>

// Problem constants
#define NB      20000      // nodes per batch
#define BATCH   4
#define KNN     16
#define DD      128        // embedding dim
#define M_TOTAL (BATCH*NB) // 80000 rows
#define BM      64         // nodes per block
#define MW      136        // bf16 LDS row stride (mean / h), padded from 128
#define UW      132        // f32  LDS row stride (upd), padded from 128
#define MAIN_LDS_BYTES (BM*UW*4)   // 33792 >= BM*MW*2 (17408)
#define NSLOT   157        // blocks per XCD slot (2*157*64 >= 20000 rows/batch)
#define GRID_MAIN (8*NSLOT)

typedef __attribute__((ext_vector_type(8))) short          bf16x8;
typedef __attribute__((ext_vector_type(4))) float          f32x4;
typedef __attribute__((ext_vector_type(4))) int            i32x4;
typedef __attribute__((ext_vector_type(8))) unsigned short u16x8;

__device__ __forceinline__ unsigned short f2bf(float f) {
    unsigned int u = __float_as_uint(f);
    u += 0x7fffu + ((u >> 16) & 1u);           // round-to-nearest-even
    return (unsigned short)(u >> 16);
}
__device__ __forceinline__ float bf2f(unsigned short u) {
    return __uint_as_float((unsigned int)u << 16);
}

// ---- weights prep: fold concat into W1a = W1x+W1d, W1b = W1m-W1d (transposed,
//      bf16 [col][k]); W2 -> W2T. 3*16384 elems, 192 blocks.
__global__ __launch_bounds__(256) void nr_prep_w(
    const float* __restrict__ W1, const float* __restrict__ W2,
    unsigned short* __restrict__ W1aT, unsigned short* __restrict__ W1bT,
    unsigned short* __restrict__ W2T)
{
    int tid = blockIdx.x * 256 + threadIdx.x;   // < 49152
    int col = (tid & 16383) / DD;
    int k   = (tid & 16383) % DD;
    if (tid < 16384) {
        W1aT[tid] = f2bf(W1[k * DD + col] + W1[(256 + k) * DD + col]);
    } else if (tid < 32768) {
        W1bT[tid - 16384] = f2bf(W1[(128 + k) * DD + col] - W1[(256 + k) * DD + col]);
    } else {
        W2T[tid - 32768] = f2bf(W2[k * DD + col]);
    }
}

// ---- emb prep: contiguous f32 -> bf16, 8 elems/thread (5000 blocks)
__global__ __launch_bounds__(256) void nr_prep_emb(
    const float* __restrict__ src, unsigned short* __restrict__ dst)
{
    long long i = ((long long)blockIdx.x * 256 + threadIdx.x) * 8;
    const float4* p = (const float4*)(src + i);
    float4 a = p[0], b = p[1];
    u16x8 o;
    o[0]=f2bf(a.x); o[1]=f2bf(a.y); o[2]=f2bf(a.z); o[3]=f2bf(a.w);
    o[4]=f2bf(b.x); o[5]=f2bf(b.y); o[6]=f2bf(b.z); o[7]=f2bf(b.w);
    *(u16x8*)(dst + i) = o;
}

// MODE 0: bf16 table (embh = full B*N row table). MODE 2: f32 fallback.
// Grid is 8*NSLOT; blockIdx&7 selects the XCD (round-robin dispatch);
// XCD pair (x>>1) owns one batch so each XCD L2 sees only that batch's table.
template<int MODE>
__global__ __launch_bounds__(256, 4) void nr_main(
    const float* __restrict__ emb, const unsigned short* __restrict__ embh,
    const int* __restrict__ knn,
    const unsigned short* __restrict__ W1aT, const unsigned short* __restrict__ W1bT,
    const unsigned short* __restrict__ W2T,
    const float* __restrict__ b1, const float* __restrict__ b2,
    float* __restrict__ out)
{
    extern __shared__ unsigned short lds[];     // phase1: mean bf16 [64][MW]
                                                // phase2b: h bf16 [64][MW]
                                                // epilogue: upd f32 [64][UW]
    unsigned short* ldsx = lds + MAIN_LDS_BYTES / 2;   // MODE2 only: x bf16

    const int t     = threadIdx.x;
    const int xcd   = blockIdx.x & 7;
    const int slot  = blockIdx.x >> 3;          // 0..NSLOT-1
    const int batch = xcd >> 1;
    const int bib   = (xcd & 1) * NSLOT + slot; // 0..313
    const int m_base = batch * NB + bib * BM;
    const int mend   = batch * NB + NB;

    // -------- Phase 1: gather 16 neighbors, mean -> LDS (bf16)
    {
        const int node_local = t >> 2;          // 0..63
        const int dpart      = t & 3;           // 32 dims each
        int m = m_base + node_local;
        if (m >= mend) m = mend - 1;            // tail dup (results discarded)

        int idx[KNN];
        const i32x4* kp4 = (const i32x4*)(knn + (long long)m * KNN);
        #pragma unroll
        for (int q = 0; q < 4; ++q) {
            i32x4 v = __builtin_nontemporal_load(kp4 + q);
            idx[4*q+0] = v[0]; idx[4*q+1] = v[1]; idx[4*q+2] = v[2]; idx[4*q+3] = v[3];
        }

        float sm[32];
        #pragma unroll
        for (int e = 0; e < 32; ++e) sm[e] = 0.f;

        if constexpr (MODE == 0) {
            const unsigned short* nb_base =
                embh + (long long)batch * NB * DD + dpart * 32;
            #pragma unroll 4
            for (int k = 0; k < KNN; ++k) {
                const u16x8* np = (const u16x8*)(nb_base + (long long)idx[k] * DD);
                #pragma unroll
                for (int j = 0; j < 4; ++j) {
                    u16x8 v = np[j];
                    #pragma unroll
                    for (int e = 0; e < 8; ++e) sm[j*8+e] += bf2f(v[e]);
                }
            }
        } else {
            // f32 fallback: also build x (bf16) in ldsx
            const float4* xp = (const float4*)(emb + (long long)m * DD + dpart * 32);
            unsigned short* xrow = ldsx + node_local * MW + dpart * 32;
            #pragma unroll
            for (int j = 0; j < 8; ++j) {
                float4 v = xp[j];
                xrow[j*4+0]=f2bf(v.x); xrow[j*4+1]=f2bf(v.y);
                xrow[j*4+2]=f2bf(v.z); xrow[j*4+3]=f2bf(v.w);
            }
            const long long bbase = (long long)batch * NB * DD + dpart * 32;
            #pragma unroll 4
            for (int k = 0; k < KNN; ++k) {
                const float4* np = (const float4*)(emb + bbase + (long long)idx[k] * DD);
                #pragma unroll
                for (int j = 0; j < 8; ++j) {
                    float4 v = np[j];
                    sm[j*4+0]+=v.x; sm[j*4+1]+=v.y; sm[j*4+2]+=v.z; sm[j*4+3]+=v.w;
                }
            }
        }

        unsigned short* mrow = lds + node_local * MW + dpart * 32;
        #pragma unroll
        for (int j = 0; j < 4; ++j) {
            u16x8 pm;
            #pragma unroll
            for (int e = 0; e < 8; ++e) pm[e] = f2bf(sm[j*8+e] * 0.0625f);
            *(u16x8*)(mrow + j*8) = pm;
        }
    }
    __syncthreads();

    // -------- Phase 2: GEMM1  h_pre = x@W1a + m@W1b  (K=128 each)
    const int wave = t >> 6;
    const int lane = t & 63;
    const int lrow = lane & 15;                 // A row / B col / D col
    const int lk   = lane >> 4;                 // 0..3

    const int row_g = m_base + wave * 16 + lrow;
    const int rowA  = (row_g < mend) ? row_g : (mend - 1);

    bf16x8 xf[4], mf[4];
    if constexpr (MODE == 0) {
        const unsigned short* xr = embh + (long long)rowA * DD + lk * 8;
        #pragma unroll
        for (int ks = 0; ks < 4; ++ks) xf[ks] = *(const bf16x8*)(xr + ks * 32);
    } else {
        const unsigned short* xr = ldsx + (wave * 16 + lrow) * MW + lk * 8;
        #pragma unroll
        for (int ks = 0; ks < 4; ++ks) xf[ks] = *(const bf16x8*)(xr + ks * 32);
    }
    {
        const unsigned short* mr = lds + (wave * 16 + lrow) * MW + lk * 8;
        #pragma unroll
        for (int ks = 0; ks < 4; ++ks) mf[ks] = *(const bf16x8*)(mr + ks * 32);
    }

    f32x4 acc[8];
    #pragma unroll
    for (int f = 0; f < 8; ++f) acc[f] = (f32x4){0.f, 0.f, 0.f, 0.f};

    #pragma unroll
    for (int ks = 0; ks < 4; ++ks) {
        #pragma unroll
        for (int f = 0; f < 8; ++f) {
            int col = f * 16 + lrow;
            bf16x8 bw = *(const bf16x8*)(W1aT + col * DD + ks * 32 + lk * 8);
            acc[f] = __builtin_amdgcn_mfma_f32_16x16x32_bf16(xf[ks], bw, acc[f], 0, 0, 0);
        }
    }
    #pragma unroll
    for (int ks = 0; ks < 4; ++ks) {
        #pragma unroll
        for (int f = 0; f < 8; ++f) {
            int col = f * 16 + lrow;
            bf16x8 bw = *(const bf16x8*)(W1bT + col * DD + ks * 32 + lk * 8);
            acc[f] = __builtin_amdgcn_mfma_f32_16x16x32_bf16(mf[ks], bw, acc[f], 0, 0, 0);
        }
    }
    __syncthreads();                            // mean reads done -> overwrite with h

    // epilogue 1: bias + exact GELU -> h (bf16) into SAME LDS region
    #pragma unroll
    for (int f = 0; f < 8; ++f) {
        int col = f * 16 + lrow;
        float bb = b1[col];
        #pragma unroll
        for (int r = 0; r < 4; ++r) {
            int row = wave * 16 + lk * 4 + r;
            float xg = acc[f][r] + bb;
            float hv = 0.5f * xg * (1.0f + erff(xg * 0.70710678118654752f));
            lds[row * MW + col] = f2bf(hv);
        }
    }
    __syncthreads();

    // -------- Phase 3: GEMM2  upd = h @ W2
    f32x4 acc2[8];
    #pragma unroll
    for (int f = 0; f < 8; ++f) acc2[f] = (f32x4){0.f, 0.f, 0.f, 0.f};
    {
        const unsigned short* abase = lds + (wave * 16 + lrow) * MW + lk * 8;
        #pragma unroll
        for (int ks = 0; ks < 4; ++ks) {
            bf16x8 af = *(const bf16x8*)(abase + ks * 32);
            #pragma unroll
            for (int f = 0; f < 8; ++f) {
                int col = f * 16 + lrow;
                bf16x8 bw = *(const bf16x8*)(W2T + col * DD + ks * 32 + lk * 8);
                acc2[f] = __builtin_amdgcn_mfma_f32_16x16x32_bf16(af, bw, acc2[f], 0, 0, 0);
            }
        }
    }
    __syncthreads();                            // h reads done -> overwrite with upd f32

    // epilogue 2a: bias -> upd f32 in LDS
    float* updl = (float*)lds;
    #pragma unroll
    for (int f = 0; f < 8; ++f) {
        int col = f * 16 + lrow;
        float bb = b2[col];
        #pragma unroll
        for (int r = 0; r < 4; ++r) {
            int row = wave * 16 + lk * 4 + r;
            updl[row * UW + col] = acc2[f][r] + bb;
        }
    }
    __syncthreads();

    // epilogue 2b: coalesced residual + store (32 consecutive f32 per thread)
    {
        const int row  = t >> 2;
        const int coff = (t & 3) * 32;
        const int rg   = m_base + row;
        if (rg < mend) {
            const float* ur = updl + row * UW + coff;
            const long long o = (long long)rg * DD + coff;
            #pragma unroll
            for (int j = 0; j < 4; ++j) {       // 8 f32 per iter
                f32x4 lo, hi;
                if constexpr (MODE == 0) {
                    u16x8 rv = *(const u16x8*)(embh + o + j * 8);
                    lo[0]=ur[j*8+0]+bf2f(rv[0]); lo[1]=ur[j*8+1]+bf2f(rv[1]);
                    lo[2]=ur[j*8+2]+bf2f(rv[2]); lo[3]=ur[j*8+3]+bf2f(rv[3]);
                    hi[0]=ur[j*8+4]+bf2f(rv[4]); hi[1]=ur[j*8+5]+bf2f(rv[5]);
                    hi[2]=ur[j*8+6]+bf2f(rv[6]); hi[3]=ur[j*8+7]+bf2f(rv[7]);
                } else {
                    const f32x4* rp = (const f32x4*)(emb + o + j * 8);
                    f32x4 r0 = rp[0], r1 = rp[1];
                    lo[0]=ur[j*8+0]+r0[0]; lo[1]=ur[j*8+1]+r0[1];
                    lo[2]=ur[j*8+2]+r0[2]; lo[3]=ur[j*8+3]+r0[3];
                    hi[0]=ur[j*8+4]+r1[0]; hi[1]=ur[j*8+5]+r1[1];
                    hi[2]=ur[j*8+6]+r1[2]; hi[3]=ur[j*8+7]+r1[3];
                }
                __builtin_nontemporal_store(lo, (f32x4*)(out + o + j * 8));
                __builtin_nontemporal_store(hi, (f32x4*)(out + o + j * 8 + 4));
            }
        }
    }
}

extern "C" void kernel_launch(void* const* d_in, const int* in_sizes, int n_in,
                              void* d_out, int out_size, void* d_ws, size_t ws_size,
                              hipStream_t stream) {
    const float* emb = (const float*)d_in[0];   // [B,N,D] f32
    const int*   knn = (const int*)  d_in[1];   // [B,N,K] i32
    const float* W1  = (const float*)d_in[2];   // [384,128]
    const float* b1  = (const float*)d_in[3];   // [128]
    const float* W2  = (const float*)d_in[4];   // [128,128]
    const float* b2  = (const float*)d_in[5];   // [128]
    float* out = (float*)d_out;

    unsigned short* W1aT = (unsigned short*)d_ws;           // 16384 u16
    unsigned short* W1bT = W1aT + 16384;                    // 16384 u16
    unsigned short* W2T  = W1bT + 16384;                    // 16384 u16
    unsigned short* embh = W2T  + 16384;                    // 10,240,000 u16

    const size_t NEED_T1 = (size_t)(49152 + 10240000) * 2;

    nr_prep_w<<<192, 256, 0, stream>>>(W1, W2, W1aT, W1bT, W2T);

    if (ws_size >= NEED_T1) {
        nr_prep_emb<<<5000, 256, 0, stream>>>(emb, embh);   // 5000*2048 = 10.24M
        nr_main<0><<<GRID_MAIN, 256, MAIN_LDS_BYTES, stream>>>(
            emb, embh, knn, W1aT, W1bT, W2T, b1, b2, out);
    } else {
        nr_main<2><<<GRID_MAIN, 256, MAIN_LDS_BYTES + BM * MW * 2, stream>>>(
            emb, nullptr, knn, W1aT, W1bT, W2T, b1, b2, out);
    }
}